// Round 2
// baseline (824.879 us; speedup 1.0000x reference)
//
#include <hip/hip_runtime.h>
#include <hip/hip_bf16.h>
#include <stdint.h>

typedef __attribute__((ext_vector_type(8))) short short8;
typedef __attribute__((ext_vector_type(4))) float floatx4;
typedef uint32_t u32;

#define N_NODES 100000
#define N_EDGES 1600000
#define ALPHA_SLOPE 0.2f
#define EPS_F 1e-16f
#define H2P_STRIDE 104   // 97 classes padded to 104 (16B-aligned rows)

static __device__ __forceinline__ float bf2f(ushort h) {
    u32 u = ((u32)h) << 16;
    return __builtin_bit_cast(float, u);
}
static __device__ __forceinline__ ushort f2bf(float f) {
    u32 u = __builtin_bit_cast(u32, f);
    u32 r = (u + 0x7fffu + ((u >> 16) & 1u)) >> 16;
    return (ushort)r;
}
static __device__ __forceinline__ float edge_e(float s) {
    float lr = s > 0.f ? s : ALPHA_SLOPE * s;
    return __expf(-lr);
}

// ---------------- prep: weight pretranspose + acol + degree histogram ----------------
// blocks [0,512): pretranspose+acol; [512,6762): hist. (feat conversion now fused into gemm staging)
__global__ __launch_bounds__(256) void prep(
    const float* __restrict__ W, const float* __restrict__ Wout,
    const float* __restrict__ a, const float* __restrict__ aout,
    const int* __restrict__ ei,
    ushort* __restrict__ Bp1, ushort* __restrict__ Bp2,
    float* __restrict__ acol1, float* __restrict__ acol2, int* __restrict__ cnt)
{
    int b = blockIdx.x;
    if (b < 512) {
        int idx = b * 256 + threadIdx.x;
        if (idx < 256 * 512) {  // Bp1: K=256, N=512
            int k = idx >> 9, n = idx & 511;
            int head = n >> 6, c = n & 63;
            Bp1[((size_t)(k >> 3) * 512 + n) * 8 + (k & 7)] = f2bf(W[head * 16384 + k * 64 + c]);
        }
        if (idx < 512 * 128) {  // Bp2: K=512, N=97 padded to 128
            int k = idx >> 7, n = idx & 127;
            ushort v = (n < 97) ? f2bf(Wout[k * 97 + n]) : (ushort)0;
            Bp2[((size_t)(k >> 3) * 128 + n) * 8 + (k & 7)] = v;
        }
        if (idx < 512) {
            int head = idx >> 6, c = idx & 63;
            acol1[idx * 2]     = a[head * 128 + c];
            acol1[idx * 2 + 1] = a[head * 128 + 64 + c];
        }
        if (idx < 128) {
            acol2[idx * 2]     = (idx < 97) ? aout[idx] : 0.f;
            acol2[idx * 2 + 1] = (idx < 97) ? aout[97 + idx] : 0.f;
        }
    } else {
        int e = (b - 512) * 256 + threadIdx.x;  // E = 1,600,000 exact
        atomicAdd(&cnt[ei[e]], 1);
    }
}

// ---------------- CSR scans ----------------
__global__ __launch_bounds__(256) void scan_partial(const int* __restrict__ cnt, int* __restrict__ bsum, int N) {
    int idx = blockIdx.x * 256 + threadIdx.x;
    int v = (idx < N) ? cnt[idx] : 0;
#pragma unroll
    for (int o = 32; o; o >>= 1) v += __shfl_xor(v, o);
    __shared__ int ws[4];
    if ((threadIdx.x & 63) == 0) ws[threadIdx.x >> 6] = v;
    __syncthreads();
    if (threadIdx.x == 0) bsum[blockIdx.x] = ws[0] + ws[1] + ws[2] + ws[3];
}

__global__ __launch_bounds__(512) void scan_block(int* __restrict__ bsum, int nb) {
    __shared__ int s[512];
    int t = threadIdx.x;
    int v = (t < nb) ? bsum[t] : 0;
    s[t] = v;
    __syncthreads();
    for (int o = 1; o < 512; o <<= 1) {
        int u = (t >= o) ? s[t - o] : 0;
        __syncthreads();
        s[t] += u;
        __syncthreads();
    }
    if (t < nb) bsum[t] = s[t] - v;  // exclusive
}

__global__ __launch_bounds__(256) void scan_final(
    const int* __restrict__ cnt, const int* __restrict__ bsum,
    int* __restrict__ row_ptr, int N, int E)
{
    int b = blockIdx.x, t = threadIdx.x;
    int idx = b * 256 + t;
    int v = (idx < N) ? cnt[idx] : 0;
    __shared__ int s[256];
    s[t] = v;
    __syncthreads();
    for (int o = 1; o < 256; o <<= 1) {
        int u = (t >= o) ? s[t - o] : 0;
        __syncthreads();
        s[t] += u;
        __syncthreads();
    }
    if (idx < N) row_ptr[idx] = bsum[b] + s[t] - v;
    if (idx == 0) row_ptr[N] = E;
}

// ---------------- layer-1 GEMM (f32 A staged->bf16) + fused score epilogue + fused fill_csr ----------------
// blocks [0,782): one 128-row panel each; internal ct-loop over the 4 col-tiles reuses the
// L2-hot A panel (feat read ~once from HBM, no featb round-trip).
// blocks [782, 782+6250): fill_csr edges (independent work hidden under the GEMM).
__global__ __launch_bounds__(256) void gemm_fill(
    const float* __restrict__ feat, const ushort* __restrict__ Bp,
    ushort* __restrict__ C, const float* __restrict__ acol,
    float* __restrict__ ssrc_arr, float* __restrict__ sdst_arr,
    const int* __restrict__ ei, const int* __restrict__ row_ptr,
    int* __restrict__ cur, int* __restrict__ col_idx)
{
    const int bx = blockIdx.x;
    if (bx >= 782) {
        // ---- fill_csr branch ----
        int e = (bx - 782) * 256 + threadIdx.x;
        int s = ei[e];
        int d = ei[N_NODES == 0 ? 0 : N_EDGES + e];  // ei[E + e]
        int p = atomicAdd(&cur[s], 1);
        col_idx[row_ptr[s] + p] = d;
        return;
    }

    // ---- GEMM branch: M=100000, K=256, NP=512 ----
    __shared__ __align__(16) ushort Ald[8 * 128 * 8];  // 16 KB
    const int tid = threadIdx.x;
    const int lane = tid & 63;
    const int wave = tid >> 6;
    const int wr = wave >> 1, wc = wave & 1;
    const int row0 = bx * 128;
    const int quad = lane >> 4;
    const int l16 = lane & 15;
    const int M = N_NODES;

#pragma unroll 1
    for (int ct = 0; ct < 4; ++ct) {
        const int col0 = ct * 128;
        floatx4 acc[4][4] = {};

        for (int k0 = 0; k0 < 256; k0 += 64) {
            __syncthreads();
#pragma unroll
            for (int i = 0; i < 4; ++i) {
                int q = i * 256 + tid;          // 1024 chunks of 16B: r = q>>3, kq = q&7
                int r = q >> 3, kq = q & 7;
                int row = row0 + r;
                if (row >= M) row = M - 1;      // clamp: garbage rows never stored
                const float4* src = (const float4*)(feat + (size_t)row * 256 + k0 + kq * 8);
                float4 f0 = src[0], f1 = src[1];
                short8 o;
                o[0] = (short)f2bf(f0.x); o[1] = (short)f2bf(f0.y);
                o[2] = (short)f2bf(f0.z); o[3] = (short)f2bf(f0.w);
                o[4] = (short)f2bf(f1.x); o[5] = (short)f2bf(f1.y);
                o[6] = (short)f2bf(f1.z); o[7] = (short)f2bf(f1.w);
                *(short8*)(&Ald[(kq * 128 + (r ^ kq)) * 8]) = o;
            }
            __syncthreads();

#pragma unroll
            for (int s = 0; s < 2; ++s) {
                int kqq = s * 4 + quad;
                int kqg = (k0 >> 3) + kqq;
                short8 bfrag[4];
#pragma unroll
                for (int nt = 0; nt < 4; ++nt) {
                    int col = col0 + wc * 64 + nt * 16 + l16;
                    bfrag[nt] = *(const short8*)(Bp + ((size_t)kqg * 512 + col) * 8);
                }
#pragma unroll
                for (int mt = 0; mt < 4; ++mt) {
                    int r = wr * 64 + mt * 16 + l16;
                    short8 afrag = *(const short8*)(&Ald[(kqq * 128 + (r ^ kqq)) * 8]);
#pragma unroll
                    for (int nt = 0; nt < 4; ++nt) {
                        acc[mt][nt] = __builtin_amdgcn_mfma_f32_16x16x32_bf16(afrag, bfrag[nt], acc[mt][nt], 0, 0, 0);
                    }
                }
            }
        }

        // C store
#pragma unroll
        for (int mt = 0; mt < 4; ++mt) {
#pragma unroll
            for (int rr = 0; rr < 4; ++rr) {
                int row = row0 + wr * 64 + mt * 16 + quad * 4 + rr;
                if (row < M) {
#pragma unroll
                    for (int nt = 0; nt < 4; ++nt) {
                        int col = col0 + wc * 64 + nt * 16 + l16;
                        C[(size_t)row * 512 + col] = f2bf(acc[mt][nt][rr]);
                    }
                }
            }
        }

        // fused score epilogue: this wave covers one 64-col group g (= head)
        float av1[4], av2[4];
#pragma unroll
        for (int nt = 0; nt < 4; ++nt) {
            int col = col0 + wc * 64 + nt * 16 + l16;
            av1[nt] = acol[col * 2];
            av2[nt] = acol[col * 2 + 1];
        }
        int g = (col0 + wc * 64) >> 6;
#pragma unroll
        for (int mt = 0; mt < 4; ++mt) {
#pragma unroll
            for (int rr = 0; rr < 4; ++rr) {
                float p1 = 0.f, p2 = 0.f;
#pragma unroll
                for (int nt = 0; nt < 4; ++nt) {
                    p1 = fmaf(acc[mt][nt][rr], av1[nt], p1);
                    p2 = fmaf(acc[mt][nt][rr], av2[nt], p2);
                }
#pragma unroll
                for (int o = 1; o < 16; o <<= 1) {
                    p1 += __shfl_xor(p1, o);
                    p2 += __shfl_xor(p2, o);
                }
                int row = row0 + wr * 64 + mt * 16 + quad * 4 + rr;
                if (l16 == 0 && row < M) {
                    atomicAdd(&ssrc_arr[(size_t)row * 8 + g], p1);
                    atomicAdd(&sdst_arr[(size_t)row * 8 + g], p2);
                }
            }
        }
    }
}

// ---------------- FUSED layer-1 aggregation + normalize + ELU + layer-2 projection + scores ----------------
// Block = 4 waves handles 16 nodes (4 per wave, sequential).
// Phase 1: wave-per-node edge aggregation, result row -> LDS Xs[16][512] bf16 (chunk-XOR swizzle).
// Phase 2: Y[16x128] = Xs @ Bp2 via mfma 16x16x32; store packed h2p (104 cols) + fused scores.
__global__ __launch_bounds__(256, 6) void ea1p(
    const int* __restrict__ row_ptr, const int* __restrict__ col_idx,
    const ushort* __restrict__ h_all, const float* __restrict__ ssrc1,
    const float* __restrict__ sdst1, const ushort* __restrict__ Bp2,
    const float* __restrict__ acol2, ushort* __restrict__ h2p,
    float* __restrict__ s2src, float* __restrict__ s2dst)
{
    __shared__ __align__(16) ushort Xs[16 * 512];  // 16 KB
    const int tid = threadIdx.x;
    const int l = tid & 63;
    const int wv = tid >> 6;
    const int hl = l >> 3;
    const int blk = blockIdx.x;

    // ---- phase 1: aggregate 4 nodes per wave ----
#pragma unroll 1
    for (int i = 0; i < 4; ++i) {
        int r = wv * 4 + i;
        int node = __builtin_amdgcn_readfirstlane(blk * 16 + r);  // wave-uniform -> scalar CSR loads
        int start = row_ptr[node], end = row_ptr[node + 1];
        float si = ssrc1[(size_t)node * 8 + hl];
        float acc[8] = {};
        float re = 0.f;
        int j = start;
        for (; j + 4 <= end; j += 4) {
            int d0 = col_idx[j], d1 = col_idx[j + 1], d2 = col_idx[j + 2], d3 = col_idx[j + 3];
            float e0 = edge_e(si + sdst1[(size_t)d0 * 8 + hl]);
            float e1 = edge_e(si + sdst1[(size_t)d1 * 8 + hl]);
            float e2 = edge_e(si + sdst1[(size_t)d2 * 8 + hl]);
            float e3 = edge_e(si + sdst1[(size_t)d3 * 8 + hl]);
            short8 v0 = *(const short8*)(h_all + (size_t)d0 * 512 + l * 8);
            short8 v1 = *(const short8*)(h_all + (size_t)d1 * 512 + l * 8);
            short8 v2 = *(const short8*)(h_all + (size_t)d2 * 512 + l * 8);
            short8 v3 = *(const short8*)(h_all + (size_t)d3 * 512 + l * 8);
            re += (e0 + e1) + (e2 + e3);
#pragma unroll
            for (int q = 0; q < 8; ++q) {
                float t0 = fmaf(e0, bf2f((ushort)v0[q]), e1 * bf2f((ushort)v1[q]));
                float t1 = fmaf(e2, bf2f((ushort)v2[q]), e3 * bf2f((ushort)v3[q]));
                acc[q] += t0 + t1;
            }
        }
        for (; j < end; ++j) {
            int d = col_idx[j];
            float e = edge_e(si + sdst1[(size_t)d * 8 + hl]);
            short8 hv = *(const short8*)(h_all + (size_t)d * 512 + l * 8);
            re += e;
#pragma unroll
            for (int q = 0; q < 8; ++q)
                acc[q] = fmaf(e, bf2f((ushort)hv[q]), acc[q]);
        }
        float inv = 1.f / (re + EPS_F);
        short8 o;
#pragma unroll
        for (int q = 0; q < 8; ++q) {
            float p = acc[q] * inv;
            p = p > 0.f ? p : expm1f(p);
            o[q] = (short)f2bf(p);
        }
        // chunk-XOR swizzled LDS store: lane l owns chunk l of row r, stored at chunk l^(r&7)
        *(short8*)(&Xs[((size_t)r * 64 + (size_t)(l ^ (r & 7))) * 8]) = o;
    }
    __syncthreads();

    // ---- phase 2: Y[16x128] = Xs[16x512] @ Bp2[512x128] ----
    const int l16 = l & 15;
    const int g = l >> 4;
    floatx4 acc2[2] = {};
#pragma unroll
    for (int s = 0; s < 16; ++s) {
        int c = s * 4 + g;                      // K-chunk (8 bf16) held by this lane group
        short8 afrag = *(const short8*)(&Xs[((size_t)l16 * 64 + (size_t)(c ^ (l16 & 7))) * 8]);
#pragma unroll
        for (int nt = 0; nt < 2; ++nt) {
            int col = wv * 32 + nt * 16 + l16;
            short8 bfrag = *(const short8*)(Bp2 + ((size_t)c * 128 + col) * 8);
            acc2[nt] = __builtin_amdgcn_mfma_f32_16x16x32_bf16(afrag, bfrag, acc2[nt], 0, 0, 0);
        }
    }

    // store packed h2p (cols < 104) + fused layer-2 score epilogue
    float av1[2], av2[2];
#pragma unroll
    for (int nt = 0; nt < 2; ++nt) {
        int col = wv * 32 + nt * 16 + l16;
        av1[nt] = acol2[col * 2];
        av2[nt] = acol2[col * 2 + 1];
    }
#pragma unroll
    for (int rr = 0; rr < 4; ++rr) {
        int row = g * 4 + rr;
        int node = blk * 16 + row;
        float p1 = 0.f, p2 = 0.f;
#pragma unroll
        for (int nt = 0; nt < 2; ++nt) {
            int col = wv * 32 + nt * 16 + l16;
            if (col < H2P_STRIDE)
                h2p[(size_t)node * H2P_STRIDE + col] = f2bf(acc2[nt][rr]);
            p1 = fmaf(acc2[nt][rr], av1[nt], p1);
            p2 = fmaf(acc2[nt][rr], av2[nt], p2);
        }
#pragma unroll
        for (int o = 1; o < 16; o <<= 1) {
            p1 += __shfl_xor(p1, o);
            p2 += __shfl_xor(p2, o);
        }
        if (l16 == 0) {
            atomicAdd(&s2src[node], p1);
            atomicAdd(&s2dst[node], p2);
        }
    }
}

// ---------------- layer-2 aggregation (inline scores) + ELU + log_softmax ----------------
// HALF-wave (32 lanes) per node; lane owns cols 4l..4l+3 of the packed 104-col h2p rows.
__global__ __launch_bounds__(256) void ea2(
    const int* __restrict__ row_ptr, const int* __restrict__ col_idx,
    const ushort* __restrict__ h2p, const float* __restrict__ s2src,
    const float* __restrict__ s2dst, float* __restrict__ out)
{
    int w = blockIdx.x * 8 + (threadIdx.x >> 5);
    int l = threadIdx.x & 31;
    const bool ldv = (l < 26);   // 26 lanes * 4 cols = 104
    int start = row_ptr[w], end = row_ptr[w + 1];
    float si = s2src[w];
    float a0 = 0.f, a1 = 0.f, a2 = 0.f, a3 = 0.f, re = 0.f;
    const ushort4 z = {0, 0, 0, 0};
    int j = start;
    for (; j + 4 <= end; j += 4) {
        int d0 = col_idx[j], d1 = col_idx[j + 1], d2 = col_idx[j + 2], d3 = col_idx[j + 3];
        float e0 = edge_e(si + s2dst[d0]);
        float e1 = edge_e(si + s2dst[d1]);
        float e2 = edge_e(si + s2dst[d2]);
        float e3 = edge_e(si + s2dst[d3]);
        ushort4 h0 = ldv ? *(const ushort4*)(h2p + (size_t)d0 * H2P_STRIDE + 4 * l) : z;
        ushort4 h1 = ldv ? *(const ushort4*)(h2p + (size_t)d1 * H2P_STRIDE + 4 * l) : z;
        ushort4 h2 = ldv ? *(const ushort4*)(h2p + (size_t)d2 * H2P_STRIDE + 4 * l) : z;
        ushort4 h3 = ldv ? *(const ushort4*)(h2p + (size_t)d3 * H2P_STRIDE + 4 * l) : z;
        re += (e0 + e1) + (e2 + e3);
        a0 += fmaf(e0, bf2f(h0.x), e1 * bf2f(h1.x)) + fmaf(e2, bf2f(h2.x), e3 * bf2f(h3.x));
        a1 += fmaf(e0, bf2f(h0.y), e1 * bf2f(h1.y)) + fmaf(e2, bf2f(h2.y), e3 * bf2f(h3.y));
        a2 += fmaf(e0, bf2f(h0.z), e1 * bf2f(h1.z)) + fmaf(e2, bf2f(h2.z), e3 * bf2f(h3.z));
        a3 += fmaf(e0, bf2f(h0.w), e1 * bf2f(h1.w)) + fmaf(e2, bf2f(h2.w), e3 * bf2f(h3.w));
    }
    for (; j < end; ++j) {
        int d = col_idx[j];
        float e = edge_e(si + s2dst[d]);
        ushort4 hv = ldv ? *(const ushort4*)(h2p + (size_t)d * H2P_STRIDE + 4 * l) : z;
        re += e;
        a0 = fmaf(e, bf2f(hv.x), a0);
        a1 = fmaf(e, bf2f(hv.y), a1);
        a2 = fmaf(e, bf2f(hv.z), a2);
        a3 = fmaf(e, bf2f(hv.w), a3);
    }
    float inv = 1.f / (re + EPS_F);
    float v[4] = { a0 * inv, a1 * inv, a2 * inv, a3 * inv };
    bool val[4];
    float m = -1e30f;
#pragma unroll
    for (int q = 0; q < 4; ++q) {
        v[q] = v[q] > 0.f ? v[q] : expm1f(v[q]);
        val[q] = (4 * l + q) < 97;
        if (val[q]) m = fmaxf(m, v[q]);
    }
#pragma unroll
    for (int o = 16; o; o >>= 1) m = fmaxf(m, __shfl_xor(m, o));  // 32-lane reduce
    float ex = 0.f;
#pragma unroll
    for (int q = 0; q < 4; ++q) ex += val[q] ? __expf(v[q] - m) : 0.f;
#pragma unroll
    for (int o = 16; o; o >>= 1) ex += __shfl_xor(ex, o);
    float lt = m + logf(ex);
#pragma unroll
    for (int q = 0; q < 4; ++q)
        if (val[q]) __builtin_nontemporal_store(v[q] - lt, out + (size_t)w * 97 + 4 * l + q);
}

extern "C" void kernel_launch(void* const* d_in, const int* in_sizes, int n_in,
                              void* d_out, int out_size, void* d_ws, size_t ws_size,
                              hipStream_t stream)
{
    const float* feat = (const float*)d_in[0];   // [N,256] f32
    const float* W    = (const float*)d_in[1];   // [8,256,64] f32
    const float* a    = (const float*)d_in[2];   // [8,128] f32
    const float* Wout = (const float*)d_in[3];   // [512,97] f32
    const float* aout = (const float*)d_in[4];   // [194] f32
    const int*   ei   = (const int*)d_in[5];     // [2,E] int32
    float* out = (float*)d_out;                  // [N,97] f32

    const int N = N_NODES, E = N_EDGES;
    const int NB = (N + 255) / 256;  // 391

    // workspace layout with lifetime aliasing (featb eliminated: gemm stages f32 feat directly)
    char* base = (char*)d_ws;
    ushort* h_all = (ushort*)(base);                 // 102,400,000 B  [gemm1 .. ea1p]
    ushort* h2p   = (ushort*)(base + 204800000);     // 20,800,000 B   [ea1p .. ea2]
    char* tail = base + 256000000;
    float* ssrc1   = (float*)(tail + 0);             // 3,200,000  [N][8]
    float* sdst1   = (float*)(tail + 3200000);       // 3,200,000  [N][8]
    float* s2src   = (float*)(tail + 6400000);       // 400,000
    float* s2dst   = (float*)(tail + 6800000);       // 400,000
    int*   row_ptr = (int*)(tail + 7200000);         // 400,128
    int*   cnt     = (int*)(tail + 7600128);         // 400,000
    int*   cur     = (int*)(tail + 8000128);         // 400,000   <- one memset covers tail..8,400,128
    int*   col_idx = (int*)(tail + 8400128);         // 6,400,000
    int*   bsum    = (int*)(tail + 14800128);        // 1,792
    ushort* Bp1    = (ushort*)(tail + 14801920);     // 262,144
    ushort* Bp2    = (ushort*)(tail + 15064064);     // 131,072
    float* acol1   = (float*)(tail + 15195136);      // 4,096
    float* acol2   = (float*)(tail + 15199232);      // 1,024   (ends tail+15,200,256)

    // single zero-fill: scores + row_ptr + cnt + cur
    hipMemsetAsync(ssrc1, 0, (size_t)8400128, stream);

    // prep: weight pretranspose + degree histogram (feat conversion moved into gemm staging)
    prep<<<6762, 256, 0, stream>>>(W, Wout, a, aout, ei, Bp1, Bp2, acol1, acol2, cnt);

    // CSR scans (need only cnt; run before the fused gemm+fill kernel)
    scan_partial<<<NB, 256, 0, stream>>>(cnt, bsum, N);
    scan_block<<<1, 512, 0, stream>>>(bsum, NB);
    scan_final<<<NB, 256, 0, stream>>>(cnt, bsum, row_ptr, N, E);

    // layer-1 projection (f32 A, ct-loop for panel reuse) + score epilogue + fused fill_csr
    gemm_fill<<<782 + 6250, 256, 0, stream>>>(feat, Bp1, h_all, acol1, ssrc1, sdst1,
                                              ei, row_ptr, cur, col_idx);

    // fused: layer-1 aggregation + layer-2 projection + layer-2 scores
    ea1p<<<N / 16, 256, 0, stream>>>(row_ptr, col_idx, h_all, ssrc1, sdst1, Bp2, acol2, h2p, s2src, s2dst);

    // layer-2 aggregation + output
    ea2<<<N / 8, 256, 0, stream>>>(row_ptr, col_idx, h2p, s2src, s2dst, out);
}

// Round 3
// 756.122 us; speedup vs baseline: 1.0909x; 1.0909x over previous
//
#include <hip/hip_runtime.h>
#include <hip/hip_bf16.h>
#include <stdint.h>

typedef __attribute__((ext_vector_type(8))) short short8;
typedef __attribute__((ext_vector_type(4))) float floatx4;
typedef uint32_t u32;

#define N_NODES 100000
#define N_EDGES 1600000
#define ALPHA_SLOPE 0.2f
#define EPS_F 1e-16f
#define H2P_STRIDE 104   // 97 classes padded to 104 (16B-aligned rows)

static __device__ __forceinline__ float bf2f(ushort h) {
    u32 u = ((u32)h) << 16;
    return __builtin_bit_cast(float, u);
}
static __device__ __forceinline__ ushort f2bf(float f) {
    u32 u = __builtin_bit_cast(u32, f);
    u32 r = (u + 0x7fffu + ((u >> 16) & 1u)) >> 16;
    return (ushort)r;
}
static __device__ __forceinline__ float edge_e(float s) {
    float lr = s > 0.f ? s : ALPHA_SLOPE * s;
    return __expf(-lr);
}

// ---------------- prep: weight pretranspose + acol + degree histogram ----------------
// blocks [0,512): pretranspose+acol; [512,6762): hist.
__global__ __launch_bounds__(256) void prep(
    const float* __restrict__ W, const float* __restrict__ Wout,
    const float* __restrict__ a, const float* __restrict__ aout,
    const int* __restrict__ ei,
    ushort* __restrict__ Bp1, ushort* __restrict__ Bp2,
    float* __restrict__ acol1, float* __restrict__ acol2, int* __restrict__ cnt)
{
    int b = blockIdx.x;
    if (b < 512) {
        int idx = b * 256 + threadIdx.x;
        if (idx < 256 * 512) {  // Bp1: K=256, N=512
            int k = idx >> 9, n = idx & 511;
            int head = n >> 6, c = n & 63;
            Bp1[((size_t)(k >> 3) * 512 + n) * 8 + (k & 7)] = f2bf(W[head * 16384 + k * 64 + c]);
        }
        if (idx < 512 * 128) {  // Bp2: K=512, N=97 padded to 128
            int k = idx >> 7, n = idx & 127;
            ushort v = (n < 97) ? f2bf(Wout[k * 97 + n]) : (ushort)0;
            Bp2[((size_t)(k >> 3) * 128 + n) * 8 + (k & 7)] = v;
        }
        if (idx < 512) {
            int head = idx >> 6, c = idx & 63;
            acol1[idx * 2]     = a[head * 128 + c];
            acol1[idx * 2 + 1] = a[head * 128 + 64 + c];
        }
        if (idx < 128) {
            acol2[idx * 2]     = (idx < 97) ? aout[idx] : 0.f;
            acol2[idx * 2 + 1] = (idx < 97) ? aout[97 + idx] : 0.f;
        }
    } else {
        int e = (b - 512) * 256 + threadIdx.x;  // E = 1,600,000 exact
        atomicAdd(&cnt[ei[e]], 1);
    }
}

// ---------------- CSR scans ----------------
__global__ __launch_bounds__(256) void scan_partial(const int* __restrict__ cnt, int* __restrict__ bsum, int N) {
    int idx = blockIdx.x * 256 + threadIdx.x;
    int v = (idx < N) ? cnt[idx] : 0;
#pragma unroll
    for (int o = 32; o; o >>= 1) v += __shfl_xor(v, o);
    __shared__ int ws[4];
    if ((threadIdx.x & 63) == 0) ws[threadIdx.x >> 6] = v;
    __syncthreads();
    if (threadIdx.x == 0) bsum[blockIdx.x] = ws[0] + ws[1] + ws[2] + ws[3];
}

__global__ __launch_bounds__(512) void scan_block(int* __restrict__ bsum, int nb) {
    __shared__ int s[512];
    int t = threadIdx.x;
    int v = (t < nb) ? bsum[t] : 0;
    s[t] = v;
    __syncthreads();
    for (int o = 1; o < 512; o <<= 1) {
        int u = (t >= o) ? s[t - o] : 0;
        __syncthreads();
        s[t] += u;
        __syncthreads();
    }
    if (t < nb) bsum[t] = s[t] - v;  // exclusive
}

// also writes cur[] = row_ptr[] (fill cursor) -> fill_csr needs no row_ptr load
__global__ __launch_bounds__(256) void scan_final(
    const int* __restrict__ cnt, const int* __restrict__ bsum,
    int* __restrict__ row_ptr, int* __restrict__ cur, int N, int E)
{
    int b = blockIdx.x, t = threadIdx.x;
    int idx = b * 256 + t;
    int v = (idx < N) ? cnt[idx] : 0;
    __shared__ int s[256];
    s[t] = v;
    __syncthreads();
    for (int o = 1; o < 256; o <<= 1) {
        int u = (t >= o) ? s[t - o] : 0;
        __syncthreads();
        s[t] += u;
        __syncthreads();
    }
    if (idx < N) {
        int rp = bsum[b] + s[t] - v;
        row_ptr[idx] = rp;
        cur[idx] = rp;
    }
    if (idx == 0) row_ptr[N] = E;
}

// fill CSR (col_idx only); cur preloaded with row offsets
__global__ __launch_bounds__(256) void fill_csr(
    const int* __restrict__ ei, int* __restrict__ cur, int* __restrict__ col_idx)
{
    int e = blockIdx.x * 256 + threadIdx.x;
    int s = ei[e];
    int d = ei[N_EDGES + e];
    int p = atomicAdd(&cur[s], 1);
    col_idx[p] = d;
}

// ---------------- layer-1 GEMM (f32 A staged->bf16 in LDS) + fused score epilogue ----------------
// 3128 blocks, one 128x128 tile each. Panel-major + XCD-chunk bijective swizzle:
// w = (b&7)*391 + (b>>3)  (3128 = 8*391 exact) -> the 4 col-tiles of a row panel sit in the
// same XCD chunk, so the A panel is fetched once per XCD L2 (no featb round-trip needed).
__global__ __launch_bounds__(256, 3) void gemm1(
    const float* __restrict__ feat, const ushort* __restrict__ Bp,
    ushort* __restrict__ C, const float* __restrict__ acol,
    float* __restrict__ ssrc_arr, float* __restrict__ sdst_arr)
{
    __shared__ __align__(16) ushort Ald[8 * 128 * 8];  // 16 KB
    const int b = blockIdx.x;
    const int w = (b & 7) * 391 + (b >> 3);
    const int rp = w >> 2, ct = w & 3;
    const int row0 = rp * 128;
    const int col0 = ct * 128;
    const int tid = threadIdx.x;
    const int lane = tid & 63;
    const int wave = tid >> 6;
    const int wr = wave >> 1, wc = wave & 1;
    const int quad = lane >> 4;
    const int l16 = lane & 15;
    const int M = N_NODES;

    floatx4 acc[4][4] = {};

    for (int k0 = 0; k0 < 256; k0 += 64) {
        __syncthreads();
#pragma unroll
        for (int i = 0; i < 4; ++i) {
            int q = i * 256 + tid;          // 1024 chunks of 16B(bf16): r = q>>3, kq = q&7
            int r = q >> 3, kq = q & 7;
            int row = row0 + r;
            if (row >= M) row = M - 1;      // clamp: garbage rows never stored
            const float4* src = (const float4*)(feat + (size_t)row * 256 + k0 + kq * 8);
            float4 f0 = src[0], f1 = src[1];
            short8 o;
            o[0] = (short)f2bf(f0.x); o[1] = (short)f2bf(f0.y);
            o[2] = (short)f2bf(f0.z); o[3] = (short)f2bf(f0.w);
            o[4] = (short)f2bf(f1.x); o[5] = (short)f2bf(f1.y);
            o[6] = (short)f2bf(f1.z); o[7] = (short)f2bf(f1.w);
            *(short8*)(&Ald[(kq * 128 + (r ^ kq)) * 8]) = o;
        }
        __syncthreads();

#pragma unroll
        for (int s = 0; s < 2; ++s) {
            int kqq = s * 4 + quad;
            int kqg = (k0 >> 3) + kqq;
            short8 bfrag[4];
#pragma unroll
            for (int nt = 0; nt < 4; ++nt) {
                int col = col0 + wc * 64 + nt * 16 + l16;
                bfrag[nt] = *(const short8*)(Bp + ((size_t)kqg * 512 + col) * 8);
            }
#pragma unroll
            for (int mt = 0; mt < 4; ++mt) {
                int r = wr * 64 + mt * 16 + l16;
                short8 afrag = *(const short8*)(&Ald[(kqq * 128 + (r ^ kqq)) * 8]);
#pragma unroll
                for (int nt = 0; nt < 4; ++nt) {
                    acc[mt][nt] = __builtin_amdgcn_mfma_f32_16x16x32_bf16(afrag, bfrag[nt], acc[mt][nt], 0, 0, 0);
                }
            }
        }
    }

    // C store
#pragma unroll
    for (int mt = 0; mt < 4; ++mt) {
#pragma unroll
        for (int rr = 0; rr < 4; ++rr) {
            int row = row0 + wr * 64 + mt * 16 + quad * 4 + rr;
            if (row < M) {
#pragma unroll
                for (int nt = 0; nt < 4; ++nt) {
                    int col = col0 + wc * 64 + nt * 16 + l16;
                    C[(size_t)row * 512 + col] = f2bf(acc[mt][nt][rr]);
                }
            }
        }
    }

    // fused score epilogue: this wave covers one 64-col group g (= head)
    float av1[4], av2[4];
#pragma unroll
    for (int nt = 0; nt < 4; ++nt) {
        int col = col0 + wc * 64 + nt * 16 + l16;
        av1[nt] = acol[col * 2];
        av2[nt] = acol[col * 2 + 1];
    }
    int g = (col0 + wc * 64) >> 6;
#pragma unroll
    for (int mt = 0; mt < 4; ++mt) {
#pragma unroll
        for (int rr = 0; rr < 4; ++rr) {
            float p1 = 0.f, p2 = 0.f;
#pragma unroll
            for (int nt = 0; nt < 4; ++nt) {
                p1 = fmaf(acc[mt][nt][rr], av1[nt], p1);
                p2 = fmaf(acc[mt][nt][rr], av2[nt], p2);
            }
#pragma unroll
            for (int o = 1; o < 16; o <<= 1) {
                p1 += __shfl_xor(p1, o);
                p2 += __shfl_xor(p2, o);
            }
            int row = row0 + wr * 64 + mt * 16 + quad * 4 + rr;
            if (l16 == 0 && row < M) {
                atomicAdd(&ssrc_arr[(size_t)row * 8 + g], p1);
                atomicAdd(&sdst_arr[(size_t)row * 8 + g], p2);
            }
        }
    }
}

// ---------------- FUSED layer-1 aggregation + normalize + ELU + layer-2 projection + scores ----------------
// Block = 4 waves handles 16 nodes (4 per wave, sequential).
// Phase 1: wave-per-node edge aggregation, result row -> LDS Xs[16][512] bf16 (chunk-XOR swizzle).
// Phase 2: Y[16x128] = Xs @ Bp2 via mfma 16x16x32; store packed h2p (104 cols) + fused scores.
__global__ __launch_bounds__(256, 6) void ea1p(
    const int* __restrict__ row_ptr, const int* __restrict__ col_idx,
    const ushort* __restrict__ h_all, const float* __restrict__ ssrc1,
    const float* __restrict__ sdst1, const ushort* __restrict__ Bp2,
    const float* __restrict__ acol2, ushort* __restrict__ h2p,
    float* __restrict__ s2src, float* __restrict__ s2dst)
{
    __shared__ __align__(16) ushort Xs[16 * 512];  // 16 KB
    const int tid = threadIdx.x;
    const int l = tid & 63;
    const int wv = tid >> 6;
    const int hl = l >> 3;
    const int blk = blockIdx.x;

    // ---- phase 1: aggregate 4 nodes per wave ----
#pragma unroll 1
    for (int i = 0; i < 4; ++i) {
        int r = wv * 4 + i;
        int node = __builtin_amdgcn_readfirstlane(blk * 16 + r);  // wave-uniform -> scalar CSR loads
        int start = row_ptr[node], end = row_ptr[node + 1];
        float si = ssrc1[(size_t)node * 8 + hl];
        float acc[8] = {};
        float re = 0.f;
        int j = start;
        for (; j + 4 <= end; j += 4) {
            int d0 = col_idx[j], d1 = col_idx[j + 1], d2 = col_idx[j + 2], d3 = col_idx[j + 3];
            float e0 = edge_e(si + sdst1[(size_t)d0 * 8 + hl]);
            float e1 = edge_e(si + sdst1[(size_t)d1 * 8 + hl]);
            float e2 = edge_e(si + sdst1[(size_t)d2 * 8 + hl]);
            float e3 = edge_e(si + sdst1[(size_t)d3 * 8 + hl]);
            short8 v0 = *(const short8*)(h_all + (size_t)d0 * 512 + l * 8);
            short8 v1 = *(const short8*)(h_all + (size_t)d1 * 512 + l * 8);
            short8 v2 = *(const short8*)(h_all + (size_t)d2 * 512 + l * 8);
            short8 v3 = *(const short8*)(h_all + (size_t)d3 * 512 + l * 8);
            re += (e0 + e1) + (e2 + e3);
#pragma unroll
            for (int q = 0; q < 8; ++q) {
                float t0 = fmaf(e0, bf2f((ushort)v0[q]), e1 * bf2f((ushort)v1[q]));
                float t1 = fmaf(e2, bf2f((ushort)v2[q]), e3 * bf2f((ushort)v3[q]));
                acc[q] += t0 + t1;
            }
        }
        for (; j < end; ++j) {
            int d = col_idx[j];
            float e = edge_e(si + sdst1[(size_t)d * 8 + hl]);
            short8 hv = *(const short8*)(h_all + (size_t)d * 512 + l * 8);
            re += e;
#pragma unroll
            for (int q = 0; q < 8; ++q)
                acc[q] = fmaf(e, bf2f((ushort)hv[q]), acc[q]);
        }
        float inv = 1.f / (re + EPS_F);
        short8 o;
#pragma unroll
        for (int q = 0; q < 8; ++q) {
            float p = acc[q] * inv;
            p = p > 0.f ? p : expm1f(p);
            o[q] = (short)f2bf(p);
        }
        // chunk-XOR swizzled LDS store: lane l owns chunk l of row r, stored at chunk l^(r&7)
        *(short8*)(&Xs[((size_t)r * 64 + (size_t)(l ^ (r & 7))) * 8]) = o;
    }
    __syncthreads();

    // ---- phase 2: Y[16x128] = Xs[16x512] @ Bp2[512x128] ----
    const int l16 = l & 15;
    const int g = l >> 4;
    floatx4 acc2[2] = {};
#pragma unroll
    for (int s = 0; s < 16; ++s) {
        int c = s * 4 + g;                      // K-chunk (8 bf16) held by this lane group
        short8 afrag = *(const short8*)(&Xs[((size_t)l16 * 64 + (size_t)(c ^ (l16 & 7))) * 8]);
#pragma unroll
        for (int nt = 0; nt < 2; ++nt) {
            int col = wv * 32 + nt * 16 + l16;
            short8 bfrag = *(const short8*)(Bp2 + ((size_t)c * 128 + col) * 8);
            acc2[nt] = __builtin_amdgcn_mfma_f32_16x16x32_bf16(afrag, bfrag, acc2[nt], 0, 0, 0);
        }
    }

    // store packed h2p (cols < 104) + fused layer-2 score epilogue
    float av1[2], av2[2];
#pragma unroll
    for (int nt = 0; nt < 2; ++nt) {
        int col = wv * 32 + nt * 16 + l16;
        av1[nt] = acol2[col * 2];
        av2[nt] = acol2[col * 2 + 1];
    }
#pragma unroll
    for (int rr = 0; rr < 4; ++rr) {
        int row = g * 4 + rr;
        int node = blk * 16 + row;
        float p1 = 0.f, p2 = 0.f;
#pragma unroll
        for (int nt = 0; nt < 2; ++nt) {
            int col = wv * 32 + nt * 16 + l16;
            if (col < H2P_STRIDE)
                h2p[(size_t)node * H2P_STRIDE + col] = f2bf(acc2[nt][rr]);
            p1 = fmaf(acc2[nt][rr], av1[nt], p1);
            p2 = fmaf(acc2[nt][rr], av2[nt], p2);
        }
#pragma unroll
        for (int o = 1; o < 16; o <<= 1) {
            p1 += __shfl_xor(p1, o);
            p2 += __shfl_xor(p2, o);
        }
        if (l16 == 0) {
            atomicAdd(&s2src[node], p1);
            atomicAdd(&s2dst[node], p2);
        }
    }
}

// ---------------- layer-2 aggregation (inline scores) + ELU + log_softmax ----------------
// HALF-wave (32 lanes) per node; lane owns cols 4l..4l+3 of the packed 104-col h2p rows.
__global__ __launch_bounds__(256) void ea2(
    const int* __restrict__ row_ptr, const int* __restrict__ col_idx,
    const ushort* __restrict__ h2p, const float* __restrict__ s2src,
    const float* __restrict__ s2dst, float* __restrict__ out)
{
    int w = blockIdx.x * 8 + (threadIdx.x >> 5);
    int l = threadIdx.x & 31;
    const bool ldv = (l < 26);   // 26 lanes * 4 cols = 104
    int start = row_ptr[w], end = row_ptr[w + 1];
    float si = s2src[w];
    float a0 = 0.f, a1 = 0.f, a2 = 0.f, a3 = 0.f, re = 0.f;
    const ushort4 z = {0, 0, 0, 0};
    int j = start;
    for (; j + 4 <= end; j += 4) {
        int d0 = col_idx[j], d1 = col_idx[j + 1], d2 = col_idx[j + 2], d3 = col_idx[j + 3];
        float e0 = edge_e(si + s2dst[d0]);
        float e1 = edge_e(si + s2dst[d1]);
        float e2 = edge_e(si + s2dst[d2]);
        float e3 = edge_e(si + s2dst[d3]);
        ushort4 h0 = ldv ? *(const ushort4*)(h2p + (size_t)d0 * H2P_STRIDE + 4 * l) : z;
        ushort4 h1 = ldv ? *(const ushort4*)(h2p + (size_t)d1 * H2P_STRIDE + 4 * l) : z;
        ushort4 h2 = ldv ? *(const ushort4*)(h2p + (size_t)d2 * H2P_STRIDE + 4 * l) : z;
        ushort4 h3 = ldv ? *(const ushort4*)(h2p + (size_t)d3 * H2P_STRIDE + 4 * l) : z;
        re += (e0 + e1) + (e2 + e3);
        a0 += fmaf(e0, bf2f(h0.x), e1 * bf2f(h1.x)) + fmaf(e2, bf2f(h2.x), e3 * bf2f(h3.x));
        a1 += fmaf(e0, bf2f(h0.y), e1 * bf2f(h1.y)) + fmaf(e2, bf2f(h2.y), e3 * bf2f(h3.y));
        a2 += fmaf(e0, bf2f(h0.z), e1 * bf2f(h1.z)) + fmaf(e2, bf2f(h2.z), e3 * bf2f(h3.z));
        a3 += fmaf(e0, bf2f(h0.w), e1 * bf2f(h1.w)) + fmaf(e2, bf2f(h2.w), e3 * bf2f(h3.w));
    }
    for (; j < end; ++j) {
        int d = col_idx[j];
        float e = edge_e(si + s2dst[d]);
        ushort4 hv = ldv ? *(const ushort4*)(h2p + (size_t)d * H2P_STRIDE + 4 * l) : z;
        re += e;
        a0 = fmaf(e, bf2f(hv.x), a0);
        a1 = fmaf(e, bf2f(hv.y), a1);
        a2 = fmaf(e, bf2f(hv.z), a2);
        a3 = fmaf(e, bf2f(hv.w), a3);
    }
    float inv = 1.f / (re + EPS_F);
    float v[4] = { a0 * inv, a1 * inv, a2 * inv, a3 * inv };
    bool val[4];
    float m = -1e30f;
#pragma unroll
    for (int q = 0; q < 4; ++q) {
        v[q] = v[q] > 0.f ? v[q] : expm1f(v[q]);
        val[q] = (4 * l + q) < 97;
        if (val[q]) m = fmaxf(m, v[q]);
    }
#pragma unroll
    for (int o = 16; o; o >>= 1) m = fmaxf(m, __shfl_xor(m, o));  // 32-lane reduce
    float ex = 0.f;
#pragma unroll
    for (int q = 0; q < 4; ++q) ex += val[q] ? __expf(v[q] - m) : 0.f;
#pragma unroll
    for (int o = 16; o; o >>= 1) ex += __shfl_xor(ex, o);
    float lt = m + logf(ex);
#pragma unroll
    for (int q = 0; q < 4; ++q)
        if (val[q]) __builtin_nontemporal_store(v[q] - lt, out + (size_t)w * 97 + 4 * l + q);
}

extern "C" void kernel_launch(void* const* d_in, const int* in_sizes, int n_in,
                              void* d_out, int out_size, void* d_ws, size_t ws_size,
                              hipStream_t stream)
{
    const float* feat = (const float*)d_in[0];   // [N,256] f32
    const float* W    = (const float*)d_in[1];   // [8,256,64] f32
    const float* a    = (const float*)d_in[2];   // [8,128] f32
    const float* Wout = (const float*)d_in[3];   // [512,97] f32
    const float* aout = (const float*)d_in[4];   // [194] f32
    const int*   ei   = (const int*)d_in[5];     // [2,E] int32
    float* out = (float*)d_out;                  // [N,97] f32

    const int N = N_NODES, E = N_EDGES;
    const int NB = (N + 255) / 256;  // 391

    // workspace layout with lifetime aliasing
    char* base = (char*)d_ws;
    ushort* h_all = (ushort*)(base);                 // 102,400,000 B  [gemm1 .. ea1p]
    ushort* h2p   = (ushort*)(base + 204800000);     // 20,800,000 B   [ea1p .. ea2]
    char* tail = base + 256000000;
    float* ssrc1   = (float*)(tail + 0);             // 3,200,000  [N][8]
    float* sdst1   = (float*)(tail + 3200000);       // 3,200,000  [N][8]
    float* s2src   = (float*)(tail + 6400000);       // 400,000
    float* s2dst   = (float*)(tail + 6800000);       // 400,000
    int*   row_ptr = (int*)(tail + 7200000);         // 400,128
    int*   cnt     = (int*)(tail + 7600128);         // 400,000   <- memset covers tail..8,000,128
    int*   cur     = (int*)(tail + 8000128);         // 400,000   (written by scan_final)
    int*   col_idx = (int*)(tail + 8400128);         // 6,400,000
    int*   bsum    = (int*)(tail + 14800128);        // 1,792
    ushort* Bp1    = (ushort*)(tail + 14801920);     // 262,144
    ushort* Bp2    = (ushort*)(tail + 15064064);     // 131,072
    float* acol1   = (float*)(tail + 15195136);      // 4,096
    float* acol2   = (float*)(tail + 15199232);      // 1,024   (ends tail+15,200,256)

    // zero-fill: scores + row_ptr + cnt (cur is fully written by scan_final)
    hipMemsetAsync(ssrc1, 0, (size_t)8000128, stream);

    // prep: weight pretranspose + degree histogram
    prep<<<6762, 256, 0, stream>>>(W, Wout, a, aout, ei, Bp1, Bp2, acol1, acol2, cnt);

    // CSR scans
    scan_partial<<<NB, 256, 0, stream>>>(cnt, bsum, N);
    scan_block<<<1, 512, 0, stream>>>(bsum, NB);
    scan_final<<<NB, 256, 0, stream>>>(cnt, bsum, row_ptr, cur, N, E);
    fill_csr<<<E / 256, 256, 0, stream>>>(ei, cur, col_idx);

    // layer-1 projection (f32 A, 3128 independent tiles, XCD-chunk swizzle) + score epilogue
    gemm1<<<3128, 256, 0, stream>>>(feat, Bp1, h_all, acol1, ssrc1, sdst1);

    // fused: layer-1 aggregation + layer-2 projection + layer-2 scores
    ea1p<<<N / 16, 256, 0, stream>>>(row_ptr, col_idx, h_all, ssrc1, sdst1, Bp2, acol2, h2p, s2src, s2dst);

    // layer-2 aggregation + output
    ea2<<<N / 8, 256, 0, stream>>>(row_ptr, col_idx, h2p, s2src, s2dst, out);
}